// Round 18
// baseline (122.733 us; speedup 1.0000x reference)
//
#include <hip/hip_runtime.h>
#include <hip/hip_fp16.h>
#include <math.h>

// Problem constants
constexpr int BS  = 8;
constexpr int NS  = 2048;
constexpr int NCP = 8;
constexpr int NH  = 8;
constexpr int C   = 128;
constexpr int HID = 128;
constexpr int RR  = 128;

constexpr int QPB = 4;    // queries per block (attn) — 128-thread blocks
constexpr int VEC = 4;    // channels per thread (attn)

constexpr int NPOS = RR * RR;                       // 16384 positions per slab
constexpr size_t PLE = (size_t)BS * NPOS * C;       // elems per plane-type slab

// transpose: 1536 blocks = 3pl x 8b x 2cg x 32q. Block = 64 ch x 512 pos.
constexpr int NBLK_T = 1536;
constexpr int QPOS   = 512;      // positions per block
constexpr int SPOS   = 256;      // positions per stage
constexpr int LROWH  = 260;      // LDS row stride in halves (520 B)

constexpr int NBINS  = 4096;     // 8 batches x 512 Morton cells (8x8x8)
constexpr int NQ     = BS * NS;  // 16384

using f4v = __attribute__((ext_vector_type(4))) float;

// ---------------------------------------------------------------------------
struct F4 { float x, y, z, w; };
__device__ __forceinline__ F4 f4add(F4 a, F4 b) {
    return F4{a.x + b.x, a.y + b.y, a.z + b.z, a.w + b.w};
}
__device__ __forceinline__ F4 f4fma(F4 acc, float s, F4 v) {
    return F4{fmaf(s, v.x, acc.x), fmaf(s, v.y, acc.y),
              fmaf(s, v.z, acc.z), fmaf(s, v.w, acc.w)};
}

// ---------------------------------------------------------------------------
// Fused transpose (fp32 [C][R][R] -> fp16 [R*R][C]) + weight prep + hist zero.
// Blocks [0,1536): transpose. [1536,1666): weight prep. [1666,1682): zero.
// ---------------------------------------------------------------------------
__global__ __launch_bounds__(256) void trans_prep_k(
    const float* __restrict__ pxz, const float* __restrict__ pxy,
    const float* __restrict__ pyz, __half* __restrict__ dst,
    const float* __restrict__ Wv, const float* __restrict__ bv,
    const float* __restrict__ Ww, const float* __restrict__ bw,
    const float* __restrict__ Wo,
    float* __restrict__ Wf, float* __restrict__ bf,
    float* __restrict__ Ww2, float* __restrict__ bw2,
    unsigned* __restrict__ hist)
{
    __shared__ __half lh[64 * LROWH];   // 33.3 KB

    const int bid = blockIdx.x;
    const int t   = threadIdx.x;

    if (bid >= NBLK_T + 130) {
        hist[(bid - (NBLK_T + 130)) * 256 + t] = 0u;
        return;
    }
    if (bid >= NBLK_T) {
        // ----- weight prep -----
        const int k = bid - NBLK_T;
        const int c = t;
        if (c >= 128) return;
        if (k < 128) {
            float acc = 0.f;
            #pragma unroll 8
            for (int j = 0; j < 128; ++j) acc += Wv[k * 128 + j] * Wo[j * 128 + c];
            Wf[k * 128 + c] = acc;
        } else if (k == 128) {
            float acc = 0.f;
            #pragma unroll 8
            for (int j = 0; j < 128; ++j) acc += bv[j] * Wo[j * 128 + c];
            bf[c] = acc;
        } else {  // k == 129
            float s[NH];
            #pragma unroll
            for (int h = 0; h < NH; ++h) s[h] = 0.f;
            #pragma unroll
            for (int i = 0; i < NCP; ++i)
                #pragma unroll
                for (int h = 0; h < NH; ++h) s[h] += Ww[c * (NCP * NH) + i * NH + h];
            #pragma unroll
            for (int h = 0; h < NH; ++h) Ww2[c * NH + h] = s[h];
            if (c < NH) {
                float tt = 0.f;
                #pragma unroll
                for (int i = 0; i < NCP; ++i) tt += bw[i * NH + c];
                bw2[c] = tt;
            }
        }
        return;
    }

    // ----- transpose block -----
    const int b    = bid & 7;
    const int rem  = bid >> 3;
    const int pl   = rem >> 6;
    const int r2   = rem & 63;
    const int cg   = r2 >> 5;
    const int q    = r2 & 31;
    const int ch0  = cg * 64;
    const int pos0 = q * QPOS;

    const float* src = (pl == 0 ? pxz : (pl == 1 ? pxy : pyz))
                       + (size_t)b * C * NPOS;
    __half* d = dst + (size_t)(pl * BS + b) * ((size_t)NPOS * C);

    const int g32  = t >> 5;
    const int l32  = t & 31;

    f4v v[16];
    #pragma unroll
    for (int i = 0; i < 16; ++i) {
        const int chL  = g32 * 8 + (i >> 1);
        const int posL = ((i & 1) << 7) + (l32 << 2);
        v[i] = __builtin_nontemporal_load(reinterpret_cast<const f4v*>(
                   src + (size_t)(ch0 + chL) * NPOS + pos0 + posL));
    }

    #pragma unroll
    for (int sc = 0; sc < 2; ++sc) {
        __syncthreads();

        #pragma unroll
        for (int i = 0; i < 16; ++i) {
            const int chL  = g32 * 8 + (i >> 1);
            const int posL = ((i & 1) << 7) + (l32 << 2);
            __half2 h0 = __floats2half2_rn(v[i][0], v[i][1]);
            __half2 h1 = __floats2half2_rn(v[i][2], v[i][3]);
            uint2 w;
            w.x = *reinterpret_cast<unsigned*>(&h0);
            w.y = *reinterpret_cast<unsigned*>(&h1);
            *reinterpret_cast<uint2*>(&lh[chL * LROWH + posL]) = w;
        }

        f4v nv[16];
        if (sc < 1) {
            #pragma unroll
            for (int i = 0; i < 16; ++i) {
                const int chL  = g32 * 8 + (i >> 1);
                const int posL = ((i & 1) << 7) + (l32 << 2);
                nv[i] = __builtin_nontemporal_load(reinterpret_cast<const f4v*>(
                            src + (size_t)(ch0 + chL) * NPOS + pos0
                                + (sc + 1) * SPOS + posL));
            }
        }
        __syncthreads();

        const int cbase = (t & 7) * 8;
        #pragma unroll
        for (int j = 0; j < 8; ++j) {
            const int p = 32 * j + (t >> 3);
            unsigned w[4];
            #pragma unroll
            for (int k = 0; k < 4; ++k) {
                const unsigned lo = *reinterpret_cast<const unsigned short*>(
                                        &lh[(cbase + 2 * k) * LROWH + p]);
                const unsigned hi = *reinterpret_cast<const unsigned short*>(
                                        &lh[(cbase + 2 * k + 1) * LROWH + p]);
                w[k] = lo | (hi << 16);
            }
            *reinterpret_cast<uint4*>(
                d + (size_t)(pos0 + sc * SPOS + p) * C + ch0 + cbase) =
                make_uint4(w[0], w[1], w[2], w[3]);
        }

        #pragma unroll
        for (int i = 0; i < 16; ++i) v[i] = nv[i];
    }
}

// ---------------------------------------------------------------------------
// Spatial binning: Morton 8x8x8 cells per batch. hist -> scan -> scatter.
// ---------------------------------------------------------------------------
__device__ __forceinline__ int bin_of(const float* qp) {
    int bx = min((int)(fminf(fmaxf(qp[0], 0.f), 1.f) * 8.f), 7);
    int by = min((int)(fminf(fmaxf(qp[1], 0.f), 1.f) * 8.f), 7);
    int bz = min((int)(fminf(fmaxf(qp[2], 0.f), 1.f) * 8.f), 7);
    int m = 0;
    #pragma unroll
    for (int i = 0; i < 3; ++i)
        m |= (((bx >> i) & 1) << (3 * i))
           | (((by >> i) & 1) << (3 * i + 1))
           | (((bz >> i) & 1) << (3 * i + 2));
    return m;
}

__global__ __launch_bounds__(256) void bin_count_k(
    const float* __restrict__ qpos, unsigned* __restrict__ hist,
    unsigned* __restrict__ binid)
{
    const int q = blockIdx.x * 256 + threadIdx.x;
    const float* qp = qpos + (size_t)q * 9;
    const int bin = ((q >> 11) << 9) | bin_of(qp);
    binid[q] = (unsigned)bin;
    atomicAdd(&hist[bin], 1u);
}

__global__ __launch_bounds__(1024) void scan_k(
    const unsigned* __restrict__ hist, unsigned* __restrict__ cursor)
{
    __shared__ unsigned s[1024];
    const int t = threadIdx.x;
    unsigned h[4];
    unsigned loc = 0;
    #pragma unroll
    for (int i = 0; i < 4; ++i) { h[i] = hist[t * 4 + i]; loc += h[i]; }
    s[t] = loc;
    __syncthreads();
    for (int off = 1; off < 1024; off <<= 1) {
        unsigned u = (t >= off) ? s[t - off] : 0u;
        __syncthreads();
        s[t] += u;
        __syncthreads();
    }
    unsigned excl = s[t] - loc;   // exclusive prefix of this thread's chunk
    #pragma unroll
    for (int i = 0; i < 4; ++i) { cursor[t * 4 + i] = excl; excl += h[i]; }
}

__global__ __launch_bounds__(256) void scatter_k(
    const unsigned* __restrict__ binid, unsigned* __restrict__ cursor,
    unsigned* __restrict__ perm)
{
    const int q = blockIdx.x * 256 + threadIdx.x;
    const unsigned pos = atomicAdd(&cursor[binid[q]], 1u);
    perm[pos] = (unsigned)q;
}

// ---------------------------------------------------------------------------
// Bilinear sample of 4 fp16 channels via packed-fp16 blend (v_pk_fma_f16).
// base already offset by batch + c4.
// ---------------------------------------------------------------------------
__device__ __forceinline__ F4 samp(const __half* __restrict__ base, float u, float v)
{
    float x = fminf(fmaxf(u, 0.f), 1.f) * (float)(RR - 1);
    float y = fminf(fmaxf(v, 0.f), 1.f) * (float)(RR - 1);
    float x0f = floorf(x), y0f = floorf(y);
    float wx = x - x0f, wy = y - y0f;
    int x0 = (int)x0f, y0 = (int)y0f;
    int x1 = min(x0 + 1, RR - 1), y1 = min(y0 + 1, RR - 1);
    int r0 = y0 << 14, r1 = y1 << 14, cc0 = x0 << 7, cc1 = x1 << 7;
    int2 a00 = *reinterpret_cast<const int2*>(base + r0 + cc0);
    int2 a01 = *reinterpret_cast<const int2*>(base + r0 + cc1);
    int2 a10 = *reinterpret_cast<const int2*>(base + r1 + cc0);
    int2 a11 = *reinterpret_cast<const int2*>(base + r1 + cc1);

    float w00f = (1.f - wx) * (1.f - wy), w01f = wx * (1.f - wy);
    float w10f = (1.f - wx) * wy,         w11f = wx * wy;
    __half2 W00 = __float2half2_rn(w00f), W01 = __float2half2_rn(w01f);
    __half2 W10 = __float2half2_rn(w10f), W11 = __float2half2_rn(w11f);

    __half2 acc0 = __hmul2(*reinterpret_cast<__half2*>(&a00.x), W00);
    __half2 acc1 = __hmul2(*reinterpret_cast<__half2*>(&a00.y), W00);
    acc0 = __hfma2(*reinterpret_cast<__half2*>(&a01.x), W01, acc0);
    acc1 = __hfma2(*reinterpret_cast<__half2*>(&a01.y), W01, acc1);
    acc0 = __hfma2(*reinterpret_cast<__half2*>(&a10.x), W10, acc0);
    acc1 = __hfma2(*reinterpret_cast<__half2*>(&a10.y), W10, acc1);
    acc0 = __hfma2(*reinterpret_cast<__half2*>(&a11.x), W11, acc0);
    acc1 = __hfma2(*reinterpret_cast<__half2*>(&a11.y), W11, acc1);

    float2 f0 = __half22float2(acc0);
    float2 f1 = __half22float2(acc1);
    return F4{f0.x, f0.y, f1.x, f1.y};
}

// ---------------------------------------------------------------------------
// Main fused kernel: 128 threads = 4 queries x 32 threads (4 channels each).
// 4096 blocks -> 16 blocks/CU (2x scheduling granularity vs QPB=8).
// ---------------------------------------------------------------------------
__global__ __launch_bounds__(128) void attn_k(
    const float* __restrict__ qpos,
    const __half* __restrict__ planes,   // [3][B][R][R][C] fp16
    const float* __restrict__ cpts,
    const unsigned* __restrict__ perm,
    const float* __restrict__ Ww2, const float* __restrict__ bw2,
    const float* __restrict__ Wf,  const float* __restrict__ bf,
    const float* __restrict__ bo,
    float* __restrict__ out)
{
    // XCD-aware swizzle: perm is (batch, Morton-cell)-sorted, batch-major.
    const int nb   = gridDim.x;
    const int cpx  = nb >> 3;
    const int sbid = (blockIdx.x & 7) * cpx + (blockIdx.x >> 3);

    const int tid  = threadIdx.x;
    const int ql   = tid >> 5;
    const int lane = tid & 31;
    const int c4   = lane * VEC;
    const int q    = (int)perm[sbid * QPB + ql];   // original query index
    const int b    = q >> 11;

    __shared__ unsigned sQ[QPB];
    if (lane == 0) sQ[ql] = (unsigned)q;

    const float* qp = qpos + (size_t)q * 9;
    const float px = qp[0], py = qp[1], pz = qp[2];
    const float a1x = qp[3], a1y = qp[4], a1z = qp[5];
    const float a2x = qp[6], a2y = qp[7], a2z = qp[8];

    float inv = 1.f / sqrtf(a1x * a1x + a1y * a1y + a1z * a1z);
    float b1x = a1x * inv, b1y = a1y * inv, b1z = a1z * inv;
    float dd  = b1x * a2x + b1y * a2y + b1z * a2z;
    float b2x = a2x - dd * b1x, b2y = a2y - dd * b1y, b2z = a2z - dd * b1z;
    inv = 1.f / sqrtf(b2x * b2x + b2y * b2y + b2z * b2z);
    b2x *= inv; b2y *= inv; b2z *= inv;
    float b3x = b1y * b2z - b1z * b2y;
    float b3y = b1z * b2x - b1x * b2z;
    float b3z = b1x * b2y - b1y * b2x;

    const __half* Pxz = planes + (size_t)b * ((size_t)NPOS * C) + c4;
    const __half* Pxy = Pxz + PLE;
    const __half* Pyz = Pxy + PLE;

    // ---- pass 1: base feature (4 channels) ----
    F4 feat = f4add(f4add(samp(Pxz, px, pz), samp(Pxy, px, py)), samp(Pyz, py, pz));

    // ---- ws[h] = feat . Ww2[:,h] + bw2[h], reduced over the 32-lane group --
    float p[NH];
    #pragma unroll
    for (int h = 0; h < NH; ++h) p[h] = 0.f;
    {
        const float* wr = Ww2 + c4 * NH;
        const float fv[VEC] = {feat.x, feat.y, feat.z, feat.w};
        #pragma unroll
        for (int i = 0; i < VEC; ++i)
            #pragma unroll
            for (int h = 0; h < NH; ++h) p[h] += fv[i] * wr[i * NH + h];
    }
    #pragma unroll
    for (int off = 16; off >= 1; off >>= 1)
        #pragma unroll
        for (int h = 0; h < NH; ++h) p[h] += __shfl_xor(p[h], off);

    float ws[NH], Ssum = 0.f;
    #pragma unroll
    for (int h = 0; h < NH; ++h) { ws[h] = p[h] + bw2[h]; Ssum += ws[h]; }

    // ---- pass 2: anchors, accumulate comb = sum_g ws[g]*sf[g] ----
    F4 comb = {0.f, 0.f, 0.f, 0.f};
    #pragma unroll 2
    for (int g = 0; g < NCP; ++g) {
        float cx = cpts[g * 3 + 0], cy = cpts[g * 3 + 1], cz = cpts[g * 3 + 2];
        float ax = px + b1x * cx + b1y * cy + b1z * cz;
        float ay = py + b2x * cx + b2y * cy + b2z * cz;
        float az = pz + b3x * cx + b3y * cy + b3z * cz;
        F4 s = f4add(f4add(samp(Pxz, ax, az), samp(Pxy, ax, ay)), samp(Pyz, ay, az));
        comb = f4fma(comb, ws[g], s);
    }

    // ---- stash per-query vectors ----
    __shared__ float sComb[QPB][C];
    __shared__ float sFeat[QPB][C];
    __shared__ float sSum[QPB];
    *reinterpret_cast<float4*>(&sComb[ql][c4]) = make_float4(comb.x, comb.y, comb.z, comb.w);
    *reinterpret_cast<float4*>(&sFeat[ql][c4]) = make_float4(feat.x, feat.y, feat.z, feat.w);
    if (lane == 0) sSum[ql] = Ssum;
    __syncthreads();

    // ---- epilogue GEMV: out[c] = comb.Wf[:,c] + Ssum*bf[c] + bo[c] + feat[c]
    const int c = tid;                // 0..127
    float acc[QPB];
    const float bfc = bf[c], boc = bo[c];
    #pragma unroll
    for (int j = 0; j < QPB; ++j)
        acc[j] = sSum[j] * bfc + boc + sFeat[j][c];
    #pragma unroll 4
    for (int k = 0; k < C; ++k) {
        float wf = Wf[k * C + c];
        #pragma unroll
        for (int j = 0; j < QPB; ++j) acc[j] += sComb[j][k] * wf;
    }
    #pragma unroll
    for (int j = 0; j < QPB; ++j)
        out[(size_t)sQ[j] * C + c] = acc[j];
}

// ---------------------------------------------------------------------------
extern "C" void kernel_launch(void* const* d_in, const int* in_sizes, int n_in,
                              void* d_out, int out_size, void* d_ws, size_t ws_size,
                              hipStream_t stream)
{
    const float* qpos = (const float*)d_in[0];
    const float* pxz  = (const float*)d_in[1];
    const float* pxy  = (const float*)d_in[2];
    const float* pyz  = (const float*)d_in[3];
    const float* cpts = (const float*)d_in[4];
    const float* Wv   = (const float*)d_in[5];
    const float* bv   = (const float*)d_in[6];
    const float* Ww   = (const float*)d_in[7];
    const float* bw   = (const float*)d_in[8];
    const float* Wo   = (const float*)d_in[9];
    const float* bo   = (const float*)d_in[10];
    float* out = (float*)d_out;

    __half* plh = (__half*)d_ws;
    float*  wsf = (float*)((char*)d_ws + 3 * PLE * sizeof(__half));  // ~96 MB in
    float* Wf  = wsf;                 // 128*128
    float* bf  = Wf + C * HID;        // 128
    float* Ww2 = bf + C;              // 128*8
    float* bw2 = Ww2 + C * NH;        // 8
    unsigned* hist   = (unsigned*)(bw2 + NH);
    unsigned* cursor = hist + NBINS;
    unsigned* binid  = cursor + NBINS;
    unsigned* perm   = binid + NQ;

    // fused transpose + weight prep + hist zero (4096 bins = 16 blocks)
    hipLaunchKernelGGL(trans_prep_k, dim3(NBLK_T + 130 + 16), dim3(256), 0, stream,
                       pxz, pxy, pyz, plh, Wv, bv, Ww, bw, Wo, Wf, bf, Ww2, bw2,
                       hist);
    // spatial binning (Morton 8x8x8 per batch)
    hipLaunchKernelGGL(bin_count_k, dim3(NQ / 256), dim3(256), 0, stream,
                       qpos, hist, binid);
    hipLaunchKernelGGL(scan_k, dim3(1), dim3(1024), 0, stream, hist, cursor);
    hipLaunchKernelGGL(scatter_k, dim3(NQ / 256), dim3(256), 0, stream,
                       binid, cursor, perm);
    // fused main kernel (4096 x 128-thread blocks)
    hipLaunchKernelGGL(attn_k, dim3(NQ / QPB), dim3(128), 0, stream,
                       qpos, plh, cpts, perm, Ww2, bw2, Wf, bf, bo, out);
}

// Round 19
// 115.823 us; speedup vs baseline: 1.0597x; 1.0597x over previous
//
#include <hip/hip_runtime.h>
#include <hip/hip_fp16.h>
#include <math.h>

// Problem constants
constexpr int BS  = 8;
constexpr int NS  = 2048;
constexpr int NCP = 8;
constexpr int NH  = 8;
constexpr int C   = 128;
constexpr int HID = 128;
constexpr int RR  = 128;

constexpr int QPB = 8;    // queries per block (attn)
constexpr int VEC = 4;    // channels per thread (attn)

constexpr int NPOS = RR * RR;                       // 16384 positions per slab
constexpr size_t PLE = (size_t)BS * NPOS * C;       // elems per plane-type slab

// transpose: 1536 blocks = 3pl x 8b x 2cg x 32q. Block = 64 ch x 512 pos.
constexpr int NBLK_T = 1536;
constexpr int QPOS   = 512;      // positions per block
constexpr int SPOS   = 256;      // positions per stage
constexpr int LROWH  = 260;      // LDS row stride in halves (520 B)

constexpr int NBINS  = 4096;     // 8 batches x 512 Morton cells (8x8x8)
constexpr int NQ     = BS * NS;  // 16384

using f4v = __attribute__((ext_vector_type(4))) float;

// ---------------------------------------------------------------------------
struct F4 { float x, y, z, w; };
__device__ __forceinline__ F4 f4add(F4 a, F4 b) {
    return F4{a.x + b.x, a.y + b.y, a.z + b.z, a.w + b.w};
}
__device__ __forceinline__ F4 f4fma(F4 acc, float s, F4 v) {
    return F4{fmaf(s, v.x, acc.x), fmaf(s, v.y, acc.y),
              fmaf(s, v.z, acc.z), fmaf(s, v.w, acc.w)};
}

// ---------------------------------------------------------------------------
// Fused transpose (fp32 [C][R][R] -> fp16 [R*R][C]) + weight prep + hist zero.
// Blocks [0,1536): transpose. [1536,1666): weight prep. [1666,1682): zero.
// ---------------------------------------------------------------------------
__global__ __launch_bounds__(256) void trans_prep_k(
    const float* __restrict__ pxz, const float* __restrict__ pxy,
    const float* __restrict__ pyz, __half* __restrict__ dst,
    const float* __restrict__ Wv, const float* __restrict__ bv,
    const float* __restrict__ Ww, const float* __restrict__ bw,
    const float* __restrict__ Wo,
    float* __restrict__ Wf, float* __restrict__ bf,
    float* __restrict__ Ww2, float* __restrict__ bw2,
    unsigned* __restrict__ hist)
{
    __shared__ __half lh[64 * LROWH];   // 33.3 KB

    const int bid = blockIdx.x;
    const int t   = threadIdx.x;

    if (bid >= NBLK_T + 130) {
        hist[(bid - (NBLK_T + 130)) * 256 + t] = 0u;
        return;
    }
    if (bid >= NBLK_T) {
        // ----- weight prep -----
        const int k = bid - NBLK_T;
        const int c = t;
        if (c >= 128) return;
        if (k < 128) {
            float acc = 0.f;
            #pragma unroll 8
            for (int j = 0; j < 128; ++j) acc += Wv[k * 128 + j] * Wo[j * 128 + c];
            Wf[k * 128 + c] = acc;
        } else if (k == 128) {
            float acc = 0.f;
            #pragma unroll 8
            for (int j = 0; j < 128; ++j) acc += bv[j] * Wo[j * 128 + c];
            bf[c] = acc;
        } else {  // k == 129
            float s[NH];
            #pragma unroll
            for (int h = 0; h < NH; ++h) s[h] = 0.f;
            #pragma unroll
            for (int i = 0; i < NCP; ++i)
                #pragma unroll
                for (int h = 0; h < NH; ++h) s[h] += Ww[c * (NCP * NH) + i * NH + h];
            #pragma unroll
            for (int h = 0; h < NH; ++h) Ww2[c * NH + h] = s[h];
            if (c < NH) {
                float tt = 0.f;
                #pragma unroll
                for (int i = 0; i < NCP; ++i) tt += bw[i * NH + c];
                bw2[c] = tt;
            }
        }
        return;
    }

    // ----- transpose block -----
    const int b    = bid & 7;
    const int rem  = bid >> 3;
    const int pl   = rem >> 6;
    const int r2   = rem & 63;
    const int cg   = r2 >> 5;
    const int q    = r2 & 31;
    const int ch0  = cg * 64;
    const int pos0 = q * QPOS;

    const float* src = (pl == 0 ? pxz : (pl == 1 ? pxy : pyz))
                       + (size_t)b * C * NPOS;
    __half* d = dst + (size_t)(pl * BS + b) * ((size_t)NPOS * C);

    const int g32  = t >> 5;
    const int l32  = t & 31;

    f4v v[16];
    #pragma unroll
    for (int i = 0; i < 16; ++i) {
        const int chL  = g32 * 8 + (i >> 1);
        const int posL = ((i & 1) << 7) + (l32 << 2);
        v[i] = __builtin_nontemporal_load(reinterpret_cast<const f4v*>(
                   src + (size_t)(ch0 + chL) * NPOS + pos0 + posL));
    }

    #pragma unroll
    for (int sc = 0; sc < 2; ++sc) {
        __syncthreads();

        #pragma unroll
        for (int i = 0; i < 16; ++i) {
            const int chL  = g32 * 8 + (i >> 1);
            const int posL = ((i & 1) << 7) + (l32 << 2);
            __half2 h0 = __floats2half2_rn(v[i][0], v[i][1]);
            __half2 h1 = __floats2half2_rn(v[i][2], v[i][3]);
            uint2 w;
            w.x = *reinterpret_cast<unsigned*>(&h0);
            w.y = *reinterpret_cast<unsigned*>(&h1);
            *reinterpret_cast<uint2*>(&lh[chL * LROWH + posL]) = w;
        }

        f4v nv[16];
        if (sc < 1) {
            #pragma unroll
            for (int i = 0; i < 16; ++i) {
                const int chL  = g32 * 8 + (i >> 1);
                const int posL = ((i & 1) << 7) + (l32 << 2);
                nv[i] = __builtin_nontemporal_load(reinterpret_cast<const f4v*>(
                            src + (size_t)(ch0 + chL) * NPOS + pos0
                                + (sc + 1) * SPOS + posL));
            }
        }
        __syncthreads();

        const int cbase = (t & 7) * 8;
        #pragma unroll
        for (int j = 0; j < 8; ++j) {
            const int p = 32 * j + (t >> 3);
            unsigned w[4];
            #pragma unroll
            for (int k = 0; k < 4; ++k) {
                const unsigned lo = *reinterpret_cast<const unsigned short*>(
                                        &lh[(cbase + 2 * k) * LROWH + p]);
                const unsigned hi = *reinterpret_cast<const unsigned short*>(
                                        &lh[(cbase + 2 * k + 1) * LROWH + p]);
                w[k] = lo | (hi << 16);
            }
            *reinterpret_cast<uint4*>(
                d + (size_t)(pos0 + sc * SPOS + p) * C + ch0 + cbase) =
                make_uint4(w[0], w[1], w[2], w[3]);
        }

        #pragma unroll
        for (int i = 0; i < 16; ++i) v[i] = nv[i];
    }
}

// ---------------------------------------------------------------------------
// Spatial binning: Morton 8x8x8 cells per batch. hist -> scan -> scatter.
// ---------------------------------------------------------------------------
__device__ __forceinline__ int bin_of(const float* qp) {
    int bx = min((int)(fminf(fmaxf(qp[0], 0.f), 1.f) * 8.f), 7);
    int by = min((int)(fminf(fmaxf(qp[1], 0.f), 1.f) * 8.f), 7);
    int bz = min((int)(fminf(fmaxf(qp[2], 0.f), 1.f) * 8.f), 7);
    int m = 0;
    #pragma unroll
    for (int i = 0; i < 3; ++i)
        m |= (((bx >> i) & 1) << (3 * i))
           | (((by >> i) & 1) << (3 * i + 1))
           | (((bz >> i) & 1) << (3 * i + 2));
    return m;
}

__global__ __launch_bounds__(256) void bin_count_k(
    const float* __restrict__ qpos, unsigned* __restrict__ hist,
    unsigned* __restrict__ binid)
{
    const int q = blockIdx.x * 256 + threadIdx.x;
    const float* qp = qpos + (size_t)q * 9;
    const int bin = ((q >> 11) << 9) | bin_of(qp);
    binid[q] = (unsigned)bin;
    atomicAdd(&hist[bin], 1u);
}

__global__ __launch_bounds__(1024) void scan_k(
    const unsigned* __restrict__ hist, unsigned* __restrict__ cursor)
{
    __shared__ unsigned s[1024];
    const int t = threadIdx.x;
    unsigned h[4];
    unsigned loc = 0;
    #pragma unroll
    for (int i = 0; i < 4; ++i) { h[i] = hist[t * 4 + i]; loc += h[i]; }
    s[t] = loc;
    __syncthreads();
    for (int off = 1; off < 1024; off <<= 1) {
        unsigned u = (t >= off) ? s[t - off] : 0u;
        __syncthreads();
        s[t] += u;
        __syncthreads();
    }
    unsigned excl = s[t] - loc;   // exclusive prefix of this thread's chunk
    #pragma unroll
    for (int i = 0; i < 4; ++i) { cursor[t * 4 + i] = excl; excl += h[i]; }
}

__global__ __launch_bounds__(256) void scatter_k(
    const unsigned* __restrict__ binid, unsigned* __restrict__ cursor,
    unsigned* __restrict__ perm)
{
    const int q = blockIdx.x * 256 + threadIdx.x;
    const unsigned pos = atomicAdd(&cursor[binid[q]], 1u);
    perm[pos] = (unsigned)q;
}

// ---------------------------------------------------------------------------
// Bilinear sample of 4 fp16 channels via packed-fp16 blend (v_pk_fma_f16).
// base already offset by batch + c4. Blend error ~5e-4 rel, negligible here.
// ---------------------------------------------------------------------------
__device__ __forceinline__ F4 samp(const __half* __restrict__ base, float u, float v)
{
    float x = fminf(fmaxf(u, 0.f), 1.f) * (float)(RR - 1);
    float y = fminf(fmaxf(v, 0.f), 1.f) * (float)(RR - 1);
    float x0f = floorf(x), y0f = floorf(y);
    float wx = x - x0f, wy = y - y0f;
    int x0 = (int)x0f, y0 = (int)y0f;
    int x1 = min(x0 + 1, RR - 1), y1 = min(y0 + 1, RR - 1);
    int r0 = y0 << 14, r1 = y1 << 14, cc0 = x0 << 7, cc1 = x1 << 7;
    int2 a00 = *reinterpret_cast<const int2*>(base + r0 + cc0);
    int2 a01 = *reinterpret_cast<const int2*>(base + r0 + cc1);
    int2 a10 = *reinterpret_cast<const int2*>(base + r1 + cc0);
    int2 a11 = *reinterpret_cast<const int2*>(base + r1 + cc1);

    float w00f = (1.f - wx) * (1.f - wy), w01f = wx * (1.f - wy);
    float w10f = (1.f - wx) * wy,         w11f = wx * wy;
    __half2 W00 = __float2half2_rn(w00f), W01 = __float2half2_rn(w01f);
    __half2 W10 = __float2half2_rn(w10f), W11 = __float2half2_rn(w11f);

    __half2 acc0 = __hmul2(*reinterpret_cast<__half2*>(&a00.x), W00);
    __half2 acc1 = __hmul2(*reinterpret_cast<__half2*>(&a00.y), W00);
    acc0 = __hfma2(*reinterpret_cast<__half2*>(&a01.x), W01, acc0);
    acc1 = __hfma2(*reinterpret_cast<__half2*>(&a01.y), W01, acc1);
    acc0 = __hfma2(*reinterpret_cast<__half2*>(&a10.x), W10, acc0);
    acc1 = __hfma2(*reinterpret_cast<__half2*>(&a10.y), W10, acc1);
    acc0 = __hfma2(*reinterpret_cast<__half2*>(&a11.x), W11, acc0);
    acc1 = __hfma2(*reinterpret_cast<__half2*>(&a11.y), W11, acc1);

    float2 f0 = __half22float2(acc0);
    float2 f1 = __half22float2(acc1);
    return F4{f0.x, f0.y, f1.x, f1.y};
}

// ---------------------------------------------------------------------------
// Main fused kernel: 256 threads = 8 queries x 32 threads (4 channels each).
// Queries taken through the spatial-sort permutation; output to original idx.
// ---------------------------------------------------------------------------
__global__ __launch_bounds__(256) void attn_k(
    const float* __restrict__ qpos,
    const __half* __restrict__ planes,   // [3][B][R][R][C] fp16
    const float* __restrict__ cpts,
    const unsigned* __restrict__ perm,
    const float* __restrict__ Ww2, const float* __restrict__ bw2,
    const float* __restrict__ Wf,  const float* __restrict__ bf,
    const float* __restrict__ bo,
    float* __restrict__ out)
{
    // XCD-aware swizzle: perm is (batch, Morton-cell)-sorted, batch-major, so
    // sbid/256 = batch -> each XCD walks one batch's cells in Morton order.
    const int nb   = gridDim.x;
    const int cpx  = nb >> 3;
    const int sbid = (blockIdx.x & 7) * cpx + (blockIdx.x >> 3);

    const int tid  = threadIdx.x;
    const int ql   = tid >> 5;
    const int lane = tid & 31;
    const int c4   = lane * VEC;
    const int q    = (int)perm[sbid * QPB + ql];   // original query index
    const int b    = q >> 11;

    __shared__ unsigned sQ[QPB];
    if (lane == 0) sQ[ql] = (unsigned)q;

    const float* qp = qpos + (size_t)q * 9;
    const float px = qp[0], py = qp[1], pz = qp[2];
    const float a1x = qp[3], a1y = qp[4], a1z = qp[5];
    const float a2x = qp[6], a2y = qp[7], a2z = qp[8];

    float inv = 1.f / sqrtf(a1x * a1x + a1y * a1y + a1z * a1z);
    float b1x = a1x * inv, b1y = a1y * inv, b1z = a1z * inv;
    float dd  = b1x * a2x + b1y * a2y + b1z * a2z;
    float b2x = a2x - dd * b1x, b2y = a2y - dd * b1y, b2z = a2z - dd * b1z;
    inv = 1.f / sqrtf(b2x * b2x + b2y * b2y + b2z * b2z);
    b2x *= inv; b2y *= inv; b2z *= inv;
    float b3x = b1y * b2z - b1z * b2y;
    float b3y = b1z * b2x - b1x * b2z;
    float b3z = b1x * b2y - b1y * b2x;

    const __half* Pxz = planes + (size_t)b * ((size_t)NPOS * C) + c4;
    const __half* Pxy = Pxz + PLE;
    const __half* Pyz = Pxy + PLE;

    // ---- pass 1: base feature (4 channels) ----
    F4 feat = f4add(f4add(samp(Pxz, px, pz), samp(Pxy, px, py)), samp(Pyz, py, pz));

    // ---- ws[h] = feat . Ww2[:,h] + bw2[h], reduced over the 32-lane group --
    float p[NH];
    #pragma unroll
    for (int h = 0; h < NH; ++h) p[h] = 0.f;
    {
        const float* wr = Ww2 + c4 * NH;
        const float fv[VEC] = {feat.x, feat.y, feat.z, feat.w};
        #pragma unroll
        for (int i = 0; i < VEC; ++i)
            #pragma unroll
            for (int h = 0; h < NH; ++h) p[h] += fv[i] * wr[i * NH + h];
    }
    #pragma unroll
    for (int off = 16; off >= 1; off >>= 1)
        #pragma unroll
        for (int h = 0; h < NH; ++h) p[h] += __shfl_xor(p[h], off);

    float ws[NH], Ssum = 0.f;
    #pragma unroll
    for (int h = 0; h < NH; ++h) { ws[h] = p[h] + bw2[h]; Ssum += ws[h]; }

    // ---- pass 2: anchors, accumulate comb = sum_g ws[g]*sf[g] ----
    F4 comb = {0.f, 0.f, 0.f, 0.f};
    #pragma unroll 2
    for (int g = 0; g < NCP; ++g) {
        float cx = cpts[g * 3 + 0], cy = cpts[g * 3 + 1], cz = cpts[g * 3 + 2];
        float ax = px + b1x * cx + b1y * cy + b1z * cz;
        float ay = py + b2x * cx + b2y * cy + b2z * cz;
        float az = pz + b3x * cx + b3y * cy + b3z * cz;
        F4 s = f4add(f4add(samp(Pxz, ax, az), samp(Pxy, ax, ay)), samp(Pyz, ay, az));
        comb = f4fma(comb, ws[g], s);
    }

    // ---- stash per-query vectors ----
    __shared__ float sComb[QPB][C];
    __shared__ float sFeat[QPB][C];
    __shared__ float sSum[QPB];
    *reinterpret_cast<float4*>(&sComb[ql][c4]) = make_float4(comb.x, comb.y, comb.z, comb.w);
    *reinterpret_cast<float4*>(&sFeat[ql][c4]) = make_float4(feat.x, feat.y, feat.z, feat.w);
    if (lane == 0) sSum[ql] = Ssum;
    __syncthreads();

    // ---- epilogue GEMV: out[c] = comb.Wf[:,c] + Ssum*bf[c] + bo[c] + feat[c]
    const int c  = tid & 127;
    const int q0 = (tid >> 7) * 4;    // queries q0..q0+3
    float acc[4];
    const float bfc = bf[c], boc = bo[c];
    #pragma unroll
    for (int j = 0; j < 4; ++j)
        acc[j] = sSum[q0 + j] * bfc + boc + sFeat[q0 + j][c];
    #pragma unroll 4
    for (int k = 0; k < C; ++k) {
        float wf = Wf[k * C + c];
        #pragma unroll
        for (int j = 0; j < 4; ++j) acc[j] += sComb[q0 + j][k] * wf;
    }
    #pragma unroll
    for (int j = 0; j < 4; ++j)
        out[(size_t)sQ[q0 + j] * C + c] = acc[j];
}

// ---------------------------------------------------------------------------
extern "C" void kernel_launch(void* const* d_in, const int* in_sizes, int n_in,
                              void* d_out, int out_size, void* d_ws, size_t ws_size,
                              hipStream_t stream)
{
    const float* qpos = (const float*)d_in[0];
    const float* pxz  = (const float*)d_in[1];
    const float* pxy  = (const float*)d_in[2];
    const float* pyz  = (const float*)d_in[3];
    const float* cpts = (const float*)d_in[4];
    const float* Wv   = (const float*)d_in[5];
    const float* bv   = (const float*)d_in[6];
    const float* Ww   = (const float*)d_in[7];
    const float* bw   = (const float*)d_in[8];
    const float* Wo   = (const float*)d_in[9];
    const float* bo   = (const float*)d_in[10];
    float* out = (float*)d_out;

    __half* plh = (__half*)d_ws;
    float*  wsf = (float*)((char*)d_ws + 3 * PLE * sizeof(__half));  // ~96 MB in
    float* Wf  = wsf;                 // 128*128
    float* bf  = Wf + C * HID;        // 128
    float* Ww2 = bf + C;              // 128*8
    float* bw2 = Ww2 + C * NH;        // 8
    unsigned* hist   = (unsigned*)(bw2 + NH);
    unsigned* cursor = hist + NBINS;
    unsigned* binid  = cursor + NBINS;
    unsigned* perm   = binid + NQ;

    // fused transpose + weight prep + hist zero (4096 bins = 16 blocks)
    hipLaunchKernelGGL(trans_prep_k, dim3(NBLK_T + 130 + 16), dim3(256), 0, stream,
                       pxz, pxy, pyz, plh, Wv, bv, Ww, bw, Wo, Wf, bf, Ww2, bw2,
                       hist);
    // spatial binning (Morton 8x8x8 per batch)
    hipLaunchKernelGGL(bin_count_k, dim3(NQ / 256), dim3(256), 0, stream,
                       qpos, hist, binid);
    hipLaunchKernelGGL(scan_k, dim3(1), dim3(1024), 0, stream, hist, cursor);
    hipLaunchKernelGGL(scatter_k, dim3(NQ / 256), dim3(256), 0, stream,
                       binid, cursor, perm);
    // fused main kernel
    hipLaunchKernelGGL(attn_k, dim3(NQ / QPB), dim3(256), 0, stream,
                       qpos, plh, cpts, perm, Ww2, bw2, Wf, bf, bo, out);
}